// Round 8
// baseline (3278.680 us; speedup 1.0000x reference)
//
#include <hip/hip_runtime.h>

// Persistent cooperative LSTM decoder. NLAYERS=4, NHID=1024, NOUT=512, BSZ=64, STEPS=128.
// 256 blocks x 512 threads, 1 block/CU. Block (lyr, jt) owns 16 hidden cols of layer lyr.
// - U/W gate weights: K 0..767 in LDS (96KB, swizzled); K 768.. in registers
// - c state in LDS; h state bf16 ping-pong in ws, stores sc1 (straight to Infinity Cache)
// - A-operand loads: PLAIN global_load_dwordx4 (L2-cached, shared by ~32 blocks/XCD);
//   one buffer_inv sc1 per block per wave (acquire half only; no wbl2 - all global
//   writes in the loop are sc1 so no dirty L2 lines) makes the L2 copies fresh.
//   Round 6 was IC-BW-bound at ~5 TB/s (64 MB A re-reads per wave); L2 sharing cuts
//   unique IC traffic ~8x.
// - sync: two-level global gridbar (round-6 verified; round-7 dataflow counters REGRESSED)
// - projection done by a separate batched GEMM (proj_kernel) on a hy3 history buffer.

#define H      1024
#define B      64
#define NL     4
#define BH     (B * H)
#define NOUTD  512
#define NSCAN  127
#define NWAVES 130
#define RSTR   76   // transposed reduce stride (floats)
#define KL     768  // K columns resident in LDS per gate-row

typedef __attribute__((ext_vector_type(8))) short short8;
typedef __attribute__((ext_vector_type(4))) float f32x4;

__device__ __forceinline__ unsigned short f2bf(float x) {
  union { float f; unsigned int u; } v; v.f = x;
  unsigned int r = v.u + 0x7FFFu + ((v.u >> 16) & 1u);
  return (unsigned short)(r >> 16);
}
__device__ __forceinline__ short8 pack8(float4 a, float4 b) {
  short8 r;
  r[0] = (short)f2bf(a.x); r[1] = (short)f2bf(a.y);
  r[2] = (short)f2bf(a.z); r[3] = (short)f2bf(a.w);
  r[4] = (short)f2bf(b.x); r[5] = (short)f2bf(b.y);
  r[6] = (short)f2bf(b.z); r[7] = (short)f2bf(b.w);
  return r;
}
__device__ __forceinline__ float sigmoidf_(float x) {
  return 1.0f / (1.0f + __expf(-x));
}
__device__ __forceinline__ float tanhf_(float x) {
  float ax = fabsf(x);
  float t = __expf(-2.0f * ax);
  float r = 1.0f - 2.0f * t / (1.0f + t);
  return copysignf(r, x);
}

// plain (L2-cached) 16B load, async: consume only after a vmcnt wait.
__device__ __forceinline__ void ldg16(short8* d, const unsigned short* p) {
  asm volatile("global_load_dwordx4 %0, %1, off" : "=v"(*d) : "v"(p));
}
#define VMWAIT4 do { asm volatile("s_waitcnt vmcnt(4)" ::: "memory"); \
                     __builtin_amdgcn_sched_barrier(0); } while (0)
#define VMWAIT0 do { asm volatile("s_waitcnt vmcnt(0)" ::: "memory"); \
                     __builtin_amdgcn_sched_barrier(0); } while (0)
// acquire-invalidate: drop clean L1/L2 lines so next loads pull fresh IC data.
#define L2INV   do { asm volatile("buffer_inv sc1" ::: "memory"); } while (0)

__device__ __forceinline__ void st_h4(unsigned short* p, unsigned v) {
  __hip_atomic_store((unsigned*)p, v, __ATOMIC_RELAXED, __HIP_MEMORY_SCOPE_AGENT);
}

// Two-level grid barrier, fence-free (round-5/6 verified).
__device__ __forceinline__ void gridbar(unsigned* bar, unsigned n) {
  asm volatile("s_waitcnt vmcnt(0)" ::: "memory");
  __syncthreads();
  if (threadIdx.x == 0) {
    const int g = blockIdx.x >> 5;
    unsigned* gcnt = bar + g * 32;
    unsigned* ggen = bar + 256 + g * 32;
    unsigned* rcnt = bar + 512;
    unsigned* rgen = bar + 544;
    unsigned a = __hip_atomic_fetch_add(gcnt, 1u, __ATOMIC_RELAXED, __HIP_MEMORY_SCOPE_AGENT);
    if (a == 31) {
      unsigned ra = __hip_atomic_fetch_add(rcnt, 1u, __ATOMIC_RELAXED, __HIP_MEMORY_SCOPE_AGENT);
      if (ra == 7) {
        __hip_atomic_store(rcnt, 0u, __ATOMIC_RELAXED, __HIP_MEMORY_SCOPE_AGENT);
        __hip_atomic_store(rgen, n, __ATOMIC_RELAXED, __HIP_MEMORY_SCOPE_AGENT);
      } else {
        while (__hip_atomic_load(rgen, __ATOMIC_RELAXED, __HIP_MEMORY_SCOPE_AGENT) < n)
          __builtin_amdgcn_s_sleep(1);
      }
      __hip_atomic_store(gcnt, 0u, __ATOMIC_RELAXED, __HIP_MEMORY_SCOPE_AGENT);
      __hip_atomic_store(ggen, n, __ATOMIC_RELAXED, __HIP_MEMORY_SCOPE_AGENT);
    } else {
      while (__hip_atomic_load(ggen, __ATOMIC_RELAXED, __HIP_MEMORY_SCOPE_AGENT) < n)
        __builtin_amdgcn_s_sleep(1);
    }
    asm volatile("" ::: "memory");
  }
  __syncthreads();
}

__global__ __launch_bounds__(512, 2)
__attribute__((amdgpu_waves_per_eu(2, 2)))
void lstm_persist(
    const float* __restrict__ hx, const float* __restrict__ cx,
    const float* __restrict__ Wm, const float* __restrict__ Um,
    unsigned short* __restrict__ hb, unsigned short* __restrict__ hist,
    unsigned* __restrict__ bar) {
  __shared__ __align__(16) unsigned short WuL[64 * KL];    // 96 KB swizzled gate weights
  __shared__ __align__(16) float red[2][64 * RSTR];        // 38.9 KB transposed reduce
  __shared__ float cS[B * 16];                             // 4 KB cell state

  const int tid = threadIdx.x;
  const int q = tid >> 6;            // wave 0..7
  const int lane = tid & 63;
  const int l15 = lane & 15;
  const int lhi = lane >> 4;
  const int bid = blockIdx.x;
  const int lyr = bid >> 6;          // 0..3
  const int jt = bid & 63;           // 16-col group

  // ---------------- init: h (both ping-pong buffers) + c + hist[0] ----------------
  {
    const int u = tid * 2;
    const int b = u >> 4, jj = u & 15;      // jj even
    const size_t gi = (size_t)lyr * BH + (size_t)b * H + jt * 16 + jj;
    const unsigned hv = (unsigned)f2bf(hx[gi]) | ((unsigned)f2bf(hx[gi + 1]) << 16);
    st_h4(hb + gi, hv);
    st_h4(hb + (size_t)NL * BH + gi, hv);
    if (lyr == 3) st_h4(hist + (size_t)b * H + jt * 16 + jj, hv);
    cS[b * 16 + jj] = cx[gi];
    cS[b * 16 + jj + 1] = cx[gi + 1];
  }

  // ---------------- weights: LDS part (K 0..767), swizzled ----------------
  {
    const int lr = tid >> 3;                 // local gate row 0..63
    const int kb0 = (tid & 7) * 96;          // K base (96 cols per thread)
    const int gr = (lr >> 4) * 1024 + jt * 16 + (lr & 15);
    const float* src = Um + ((size_t)lyr * 4096 + gr) * 1024 + kb0;
#pragma unroll
    for (int jc = 0; jc < 12; ++jc) {
      float4 f0 = *(const float4*)(src + jc * 8);
      float4 f1 = *(const float4*)(src + jc * 8 + 4);
      int byteoff = ((lr * KL + kb0 + jc * 8) * 2) ^ ((lr & 7) << 4);
      *(short8*)((char*)WuL + byteoff) = pack8(f0, f1);
    }
  }

  // ---------------- register weights (K >= 768): 5 chunks lyr>0, 1 chunk lyr0 ----------------
  short8 wreg[5][4];
  if (lyr == 0) {
    const int kk = KL + 32 * q + 8 * lhi;    // 768..1023
#pragma unroll
    for (int n = 0; n < 4; ++n) {
      const int gr = n * 1024 + jt * 16 + l15;
      const float* src = Um + (size_t)gr * 1024 + kk;
      wreg[0][n] = pack8(*(const float4*)src, *(const float4*)(src + 4));
    }
  } else {
#pragma unroll
    for (int c = 0; c < 5; ++c) {
      const int kk = KL + 160 * q + 32 * c + 8 * lhi;   // 768..2047
#pragma unroll
      for (int n = 0; n < 4; ++n) {
        const int gr = n * 1024 + jt * 16 + l15;
        const float* src = (kk < 1024)
            ? (Um + ((size_t)lyr * 4096 + gr) * 1024 + kk)
            : (Wm + ((size_t)(lyr - 1) * 4096 + gr) * 1024 + (kk - 1024));
        wreg[c][n] = pack8(*(const float4*)src, *(const float4*)(src + 4));
      }
    }
  }

  unsigned barn = 1;
  gridbar(bar, barn++);

  // ---------------- wavefront loop ----------------
  for (int w = 0; w < NWAVES; ++w) {
    const int rd = (w + 1) & 1, wr = w & 1;
    const unsigned short* hrd = hb + (size_t)rd * NL * BH;
    unsigned short* hwr = hb + (size_t)wr * NL * BH;
    const int s = w - lyr;

    if (s >= 0 && s < NSCAN) {
      L2INV;  // discard stale clean L1/L2 copies of the h buffers; re-pull from IC once per XCD

      const unsigned short* baseU = hrd + (size_t)lyr * BH;
      const unsigned short* baseW = hrd + (size_t)(lyr > 0 ? lyr - 1 : 0) * BH;
      const unsigned short* aU = baseU + (size_t)l15 * H + 8 * lhi;
      const unsigned short* aW = baseW + (size_t)l15 * H + 8 * lhi;

      f32x4 acc[4][4];
#pragma unroll
      for (int m = 0; m < 4; ++m)
#pragma unroll
        for (int n = 0; n < 4; ++n) acc[m][n] = (f32x4){0.f, 0.f, 0.f, 0.f};

      short8 A[2][4];

#define KCOL0(c)  (96 * q + 32 * (c))                         // LDS-weight chunks (c<3)
#define KCOLR(c)  (KL + 160 * q + 32 * ((c) - 3))             // reg-weight chunks lyr>0
#define ISSUE(buf, k) { \
    const unsigned short* _p = ((k) < 1024) ? (aU + (k)) : (aW + ((k) - 1024)); \
    ldg16(&A[buf][0], _p); \
    ldg16(&A[buf][1], _p + 16 * H); \
    ldg16(&A[buf][2], _p + 32 * H); \
    ldg16(&A[buf][3], _p + 48 * H); }

      if (lyr > 0) {
        ISSUE(0, KCOL0(0));
        ISSUE(1, KCOL0(1));
#pragma unroll
        for (int c = 0; c < 8; ++c) {
          if (c < 7) VMWAIT4; else VMWAIT0;
          if (c < 3) {
            const int kk = KCOL0(c);
#pragma unroll
            for (int n = 0; n < 4; ++n) {
              const int byteoff = (((n * 16 + l15) * KL + kk + 8 * lhi) * 2) ^ ((l15 & 7) << 4);
              short8 bb = *(const short8*)((const char*)WuL + byteoff);
#pragma unroll
              for (int m = 0; m < 4; ++m)
                acc[m][n] = __builtin_amdgcn_mfma_f32_16x16x32_bf16(A[c & 1][m], bb, acc[m][n], 0, 0, 0);
            }
          } else {
#pragma unroll
            for (int n = 0; n < 4; ++n)
#pragma unroll
              for (int m = 0; m < 4; ++m)
                acc[m][n] = __builtin_amdgcn_mfma_f32_16x16x32_bf16(A[c & 1][m], wreg[c - 3][n], acc[m][n], 0, 0, 0);
          }
          if (c + 2 < 8) {
            const int k2 = (c + 2 < 3) ? KCOL0(c + 2) : KCOLR(c + 2);
            ISSUE(c & 1, k2);
          }
        }
      } else {
        ISSUE(0, KCOL0(0));
        ISSUE(1, KCOL0(1));
#pragma unroll
        for (int c = 0; c < 4; ++c) {
          if (c < 3) VMWAIT4; else VMWAIT0;
          if (c < 3) {
            const int kk = KCOL0(c);
#pragma unroll
            for (int n = 0; n < 4; ++n) {
              const int byteoff = (((n * 16 + l15) * KL + kk + 8 * lhi) * 2) ^ ((l15 & 7) << 4);
              short8 bb = *(const short8*)((const char*)WuL + byteoff);
#pragma unroll
              for (int m = 0; m < 4; ++m)
                acc[m][n] = __builtin_amdgcn_mfma_f32_16x16x32_bf16(A[c & 1][m], bb, acc[m][n], 0, 0, 0);
            }
          } else {
#pragma unroll
            for (int n = 0; n < 4; ++n)
#pragma unroll
              for (int m = 0; m < 4; ++m)
                acc[m][n] = __builtin_amdgcn_mfma_f32_16x16x32_bf16(A[c & 1][m], wreg[0][n], acc[m][n], 0, 0, 0);
          }
          if (c + 2 < 4) ISSUE(c & 1, KCOL0(c + 2));
        }
      }
#undef ISSUE
#undef KCOL0
#undef KCOLR

      // transposed vectorized reduce: 8 partials -> red[0] + red[1]
      __syncthreads();
      {
        const int rr = q >> 1;
        float* tile = red[q & 1];
        for (int r = 0; r < 4; ++r) {
          if (rr == r) {
#pragma unroll
            for (int m = 0; m < 4; ++m)
#pragma unroll
              for (int n = 0; n < 4; ++n) {
                float* p = &tile[(n * 16 + l15) * RSTR + m * 16 + lhi * 4];
                if (r == 0) *(f32x4*)p = acc[m][n];
                else { f32x4 v = *(f32x4*)p; v += acc[m][n]; *(f32x4*)p = v; }
              }
          }
          __syncthreads();
        }
      }

      // fused LSTM cell (2 adjacent hidden units per thread)
      {
        const int u = tid * 2;
        const int b = u >> 4, jj = u & 15;  // jj even
        unsigned short hyv[2];
#pragma unroll
        for (int e = 0; e < 2; ++e) {
          const int j2 = jj + e;
          const float ig = red[0][(0 * 16 + j2) * RSTR + b] + red[1][(0 * 16 + j2) * RSTR + b];
          const float fg = red[0][(1 * 16 + j2) * RSTR + b] + red[1][(1 * 16 + j2) * RSTR + b];
          const float gg = red[0][(2 * 16 + j2) * RSTR + b] + red[1][(2 * 16 + j2) * RSTR + b];
          const float og = red[0][(3 * 16 + j2) * RSTR + b] + red[1][(3 * 16 + j2) * RSTR + b];
          const float i_ = sigmoidf_(ig);
          const float f_ = sigmoidf_(fg);
          const float g_ = tanhf_(gg);
          const float o_ = sigmoidf_(og);
          const float cv = f_ * cS[b * 16 + j2] + i_ * g_;
          cS[b * 16 + j2] = cv;
          hyv[e] = f2bf(o_ * tanhf_(cv));
        }
        const unsigned packed = (unsigned)hyv[0] | ((unsigned)hyv[1] << 16);
        st_h4(hwr + (size_t)lyr * BH + (size_t)b * H + jt * 16 + jj, packed);
        if (lyr == 3)   // history for the batched output projection (t = s+1), sc1 (no dirty L2)
          st_h4(hist + (size_t)(s + 1) * BH + (size_t)b * H + jt * 16 + jj, packed);
      }
    }

    gridbar(bar, barn++);
  }
}

// ---------------- batched output projection: out[t] = hist[t] @ L^T ----------------
// M = 128*64 = 8192 rows, N = 512, K = 1024. grid = 128 Mtiles x 8 Ntiles, 256 thr.
__global__ __launch_bounds__(256) void proj_kernel(
    const unsigned short* __restrict__ hist, const float* __restrict__ Lm,
    float* __restrict__ out) {
  __shared__ __align__(16) unsigned short As[64 * 136];
  const int tid = threadIdx.x;
  const int q = tid >> 6;
  const int lane = tid & 63;
  const int l15 = lane & 15;
  const int lhi = lane >> 4;
  const int mt = blockIdx.x >> 3;
  const int nt = blockIdx.x & 7;

  f32x4 acc[4];
#pragma unroll
  for (int m = 0; m < 4; ++m) acc[m] = (f32x4){0.f, 0.f, 0.f, 0.f};

  for (int kb = 0; kb < 8; ++kb) {
    __syncthreads();
#pragma unroll
    for (int i = 0; i < 4; ++i) {
      int g = tid + 256 * i;
      int row = g >> 4, cu = g & 15;
      *(short8*)(&As[row * 136 + cu * 8]) =
          *(const short8*)(&hist[((size_t)mt * 64 + row) * H + kb * 128 + cu * 8]);
    }
    __syncthreads();
#pragma unroll
    for (int kk = 0; kk < 4; ++kk) {
      const int ko = kk * 32 + 8 * lhi;
      const float* src = Lm + ((size_t)nt * 64 + q * 16 + l15) * H + kb * 128 + ko;
      short8 bb = pack8(*(const float4*)src, *(const float4*)(src + 4));
#pragma unroll
      for (int m = 0; m < 4; ++m) {
        short8 a = *(const short8*)(&As[(m * 16 + l15) * 136 + ko]);
        acc[m] = __builtin_amdgcn_mfma_f32_16x16x32_bf16(a, bb, acc[m], 0, 0, 0);
      }
    }
  }
  const int col = nt * 64 + q * 16 + l15;
#pragma unroll
  for (int m = 0; m < 4; ++m)
#pragma unroll
    for (int j = 0; j < 4; ++j) {
      const int row = mt * 64 + m * 16 + lhi * 4 + j;
      out[(size_t)row * NOUTD + col] = acc[m][j];
    }
}

extern "C" void kernel_launch(void* const* d_in, const int* in_sizes, int n_in,
                              void* d_out, int out_size, void* d_ws, size_t ws_size,
                              hipStream_t stream) {
  const float* hx = (const float*)d_in[0];
  const float* cx = (const float*)d_in[1];
  const float* Wm = (const float*)d_in[2];
  const float* Um = (const float*)d_in[3];
  const float* Lm = (const float*)d_in[4];
  float* out = (float*)d_out;

  char* ws = (char*)d_ws;
  unsigned short* hb = (unsigned short*)ws;                  // 1 MB ping-pong h
  unsigned* bar = (unsigned*)(ws + (1 << 20));               // 4 KB barrier state
  unsigned short* hist = (unsigned short*)(ws + (1 << 20) + 65536);  // 16 MB hy3 history

  hipMemsetAsync(bar, 0, 4096, stream);

  void* args[] = {(void*)&hx, (void*)&cx, (void*)&Wm, (void*)&Um,
                  (void*)&hb, (void*)&hist, (void*)&bar};
  hipLaunchCooperativeKernel((const void*)lstm_persist, dim3(256), dim3(512),
                             args, 0, stream);
  proj_kernel<<<dim3(1024), dim3(256), 0, stream>>>(hist, Lm, out);
}

// Round 9
// 2634.300 us; speedup vs baseline: 1.2446x; 1.2446x over previous
//
#include <hip/hip_runtime.h>

// Persistent cooperative LSTM decoder. NLAYERS=4, NHID=1024, NOUT=512, BSZ=64, STEPS=128.
// 256 blocks x 512 threads, 1 block/CU (LDS 141KB => exactly 32 blocks per XCD).
// Round-9 change vs round-6 base (1674us): XCD-LOCAL L2 STAGING of the A-operand.
//  - each block reads its physical XCD id (s_getreg HW_REG_XCC_ID, m09) and elects rank 0..31
//  - per wave: 32 blocks/XCD copy the 512KB h read-buffer IC->per-XCD stage (plain stores,
//    dirty L2 lines private to that XCD -> coherent by construction, no fences/invalidates)
//  - A-loads then hit local L2 (sc0 = L1-bypass): chip IC traffic 56MB -> 4MB per wave.
// Everything else identical to round 6 (two-level gridbar, depth-2 vmcnt pipeline,
// 96KB LDS weights + reg weights, LDS cell state, separate proj_kernel).

#define H      1024
#define B      64
#define NL     4
#define BH     (B * H)
#define NOUTD  512
#define NSCAN  127
#define NWAVES 130
#define RSTR   76   // transposed reduce stride (floats)
#define KL     768  // K columns resident in LDS per gate-row

typedef __attribute__((ext_vector_type(8))) short short8;
typedef __attribute__((ext_vector_type(4))) float f32x4;

__device__ __forceinline__ unsigned short f2bf(float x) {
  union { float f; unsigned int u; } v; v.f = x;
  unsigned int r = v.u + 0x7FFFu + ((v.u >> 16) & 1u);
  return (unsigned short)(r >> 16);
}
__device__ __forceinline__ short8 pack8(float4 a, float4 b) {
  short8 r;
  r[0] = (short)f2bf(a.x); r[1] = (short)f2bf(a.y);
  r[2] = (short)f2bf(a.z); r[3] = (short)f2bf(a.w);
  r[4] = (short)f2bf(b.x); r[5] = (short)f2bf(b.y);
  r[6] = (short)f2bf(b.z); r[7] = (short)f2bf(b.w);
  return r;
}
__device__ __forceinline__ float sigmoidf_(float x) {
  return 1.0f / (1.0f + __expf(-x));
}
__device__ __forceinline__ float tanhf_(float x) {
  float ax = fabsf(x);
  float t = __expf(-2.0f * ax);
  float r = 1.0f - 2.0f * t / (1.0f + t);
  return copysignf(r, x);
}

// IC-coherent 16B load (L1+L2 bypass). Consume only after a vmcnt wait.
__device__ __forceinline__ void ldg16_ic(short8* d, const unsigned short* p) {
  asm volatile("global_load_dwordx4 %0, %1, off sc0 sc1" : "=v"(*d) : "v"(p));
}
// L2-served 16B load (L1 bypass only) - for XCD-local staged data.
__device__ __forceinline__ void ldg16_l2(short8* d, const unsigned short* p) {
  asm volatile("global_load_dwordx4 %0, %1, off sc0" : "=v"(*d) : "v"(p));
}
#define VMWAIT4 do { asm volatile("s_waitcnt vmcnt(4)" ::: "memory"); \
                     __builtin_amdgcn_sched_barrier(0); } while (0)
#define VMWAIT0 do { asm volatile("s_waitcnt vmcnt(0)" ::: "memory"); \
                     __builtin_amdgcn_sched_barrier(0); } while (0)

__device__ __forceinline__ void st_h4(unsigned short* p, unsigned v) {
  __hip_atomic_store((unsigned*)p, v, __ATOMIC_RELAXED, __HIP_MEMORY_SCOPE_AGENT);
}

// Two-level grid barrier, fence-free (round-5/6 verified).
__device__ __forceinline__ void gridbar(unsigned* bar, unsigned n) {
  asm volatile("s_waitcnt vmcnt(0)" ::: "memory");
  __syncthreads();
  if (threadIdx.x == 0) {
    const int g = blockIdx.x >> 5;
    unsigned* gcnt = bar + g * 32;
    unsigned* ggen = bar + 256 + g * 32;
    unsigned* rcnt = bar + 512;
    unsigned* rgen = bar + 544;
    unsigned a = __hip_atomic_fetch_add(gcnt, 1u, __ATOMIC_RELAXED, __HIP_MEMORY_SCOPE_AGENT);
    if (a == 31) {
      unsigned ra = __hip_atomic_fetch_add(rcnt, 1u, __ATOMIC_RELAXED, __HIP_MEMORY_SCOPE_AGENT);
      if (ra == 7) {
        __hip_atomic_store(rcnt, 0u, __ATOMIC_RELAXED, __HIP_MEMORY_SCOPE_AGENT);
        __hip_atomic_store(rgen, n, __ATOMIC_RELAXED, __HIP_MEMORY_SCOPE_AGENT);
      } else {
        while (__hip_atomic_load(rgen, __ATOMIC_RELAXED, __HIP_MEMORY_SCOPE_AGENT) < n)
          __builtin_amdgcn_s_sleep(1);
      }
      __hip_atomic_store(gcnt, 0u, __ATOMIC_RELAXED, __HIP_MEMORY_SCOPE_AGENT);
      __hip_atomic_store(ggen, n, __ATOMIC_RELAXED, __HIP_MEMORY_SCOPE_AGENT);
    } else {
      while (__hip_atomic_load(ggen, __ATOMIC_RELAXED, __HIP_MEMORY_SCOPE_AGENT) < n)
        __builtin_amdgcn_s_sleep(1);
    }
    asm volatile("" ::: "memory");
  }
  __syncthreads();
}

__global__ __launch_bounds__(512, 2)
__attribute__((amdgpu_waves_per_eu(2, 2)))
void lstm_persist(
    const float* __restrict__ hx, const float* __restrict__ cx,
    const float* __restrict__ Wm, const float* __restrict__ Um,
    unsigned short* __restrict__ hb, unsigned short* __restrict__ hist,
    unsigned* __restrict__ bar, unsigned short* __restrict__ stgAll) {
  __shared__ __align__(16) unsigned short WuL[64 * KL];    // 96 KB swizzled gate weights
  __shared__ __align__(16) float red[2][64 * RSTR];        // 38.9 KB transposed reduce
  __shared__ float cS[B * 16];                             // 4 KB cell state
  __shared__ int srank;

  const int tid = threadIdx.x;
  const int q = tid >> 6;            // wave 0..7
  const int lane = tid & 63;
  const int l15 = lane & 15;
  const int lhi = lane >> 4;
  const int bid = blockIdx.x;
  const int lyr = bid >> 6;          // 0..3
  const int jt = bid & 63;           // 16-col group

  // physical XCD id (HW_REG_XCC_ID = hwreg 20; size 32, offset 0 -> simm 63508)
  const int xcd = __builtin_amdgcn_s_getreg((31 << 11) | 20) & 7;
  unsigned short* stg = stgAll + (size_t)xcd * NL * BH;   // this XCD's private 512KB stage

  // ---------------- init: h (both ping-pong buffers) + c + hist[0] ----------------
  {
    const int u = tid * 2;
    const int b = u >> 4, jj = u & 15;      // jj even
    const size_t gi = (size_t)lyr * BH + (size_t)b * H + jt * 16 + jj;
    const unsigned hv = (unsigned)f2bf(hx[gi]) | ((unsigned)f2bf(hx[gi + 1]) << 16);
    st_h4(hb + gi, hv);
    st_h4(hb + (size_t)NL * BH + gi, hv);
    if (lyr == 3) *(unsigned*)(hist + (size_t)b * H + jt * 16 + jj) = hv;
    cS[b * 16 + jj] = cx[gi];
    cS[b * 16 + jj + 1] = cx[gi + 1];
  }

  // ---------------- XCD-local rank election (once) ----------------
  if (tid == 0)
    srank = (int)__hip_atomic_fetch_add(bar + 640 + xcd * 16, 1u,
                                        __ATOMIC_RELAXED, __HIP_MEMORY_SCOPE_AGENT);

  // ---------------- weights: LDS part (K 0..767), swizzled ----------------
  {
    const int lr = tid >> 3;                 // local gate row 0..63
    const int kb0 = (tid & 7) * 96;          // K base (96 cols per thread)
    const int gr = (lr >> 4) * 1024 + jt * 16 + (lr & 15);
    const float* src = Um + ((size_t)lyr * 4096 + gr) * 1024 + kb0;
#pragma unroll
    for (int jc = 0; jc < 12; ++jc) {
      float4 f0 = *(const float4*)(src + jc * 8);
      float4 f1 = *(const float4*)(src + jc * 8 + 4);
      int byteoff = ((lr * KL + kb0 + jc * 8) * 2) ^ ((lr & 7) << 4);
      *(short8*)((char*)WuL + byteoff) = pack8(f0, f1);
    }
  }

  // ---------------- register weights (K >= 768): 5 chunks lyr>0, 1 chunk lyr0 ----------------
  short8 wreg[5][4];
  if (lyr == 0) {
    const int kk = KL + 32 * q + 8 * lhi;    // 768..1023
#pragma unroll
    for (int n = 0; n < 4; ++n) {
      const int gr = n * 1024 + jt * 16 + l15;
      const float* src = Um + (size_t)gr * 1024 + kk;
      wreg[0][n] = pack8(*(const float4*)src, *(const float4*)(src + 4));
    }
  } else {
#pragma unroll
    for (int c = 0; c < 5; ++c) {
      const int kk = KL + 160 * q + 32 * c + 8 * lhi;   // 768..2047
#pragma unroll
      for (int n = 0; n < 4; ++n) {
        const int gr = n * 1024 + jt * 16 + l15;
        const float* src = (kk < 1024)
            ? (Um + ((size_t)lyr * 4096 + gr) * 1024 + kk)
            : (Wm + ((size_t)(lyr - 1) * 4096 + gr) * 1024 + (kk - 1024));
        wreg[c][n] = pack8(*(const float4*)src, *(const float4*)(src + 4));
      }
    }
  }

  __syncthreads();
  const int rank = srank & 31;           // 0..31 within this XCD
  unsigned* xbar = bar + 832 + xcd * 16;

  unsigned barn = 1;
  gridbar(bar, barn++);

  // ---------------- wavefront loop ----------------
  for (int w = 0; w < NWAVES; ++w) {
    const int rd = (w + 1) & 1, wr = w & 1;
    const unsigned short* hrd = hb + (size_t)rd * NL * BH;
    unsigned short* hwr = hb + (size_t)wr * NL * BH;
    const int s = w - lyr;

    // ---- stage: 32 blocks of this XCD copy hb[rd] (512KB) IC -> local L2 ----
    {
      const unsigned short* src = hrd + (size_t)rank * 8192 + tid * 16;  // 16KB slice
      unsigned short* dst = stg + (size_t)rank * 8192 + tid * 16;
      short8 t0, t1;
      ldg16_ic(&t0, src);
      ldg16_ic(&t1, src + 8);
      asm volatile("s_waitcnt vmcnt(0)" ::: "memory");
      *(short8*)dst = t0;
      *(short8*)(dst + 8) = t1;
    }
    asm volatile("s_waitcnt vmcnt(0)" ::: "memory");   // stores ack'd in L2
    __syncthreads();
    if (tid == 0) {
      __hip_atomic_fetch_add(xbar, 1u, __ATOMIC_RELAXED, __HIP_MEMORY_SCOPE_AGENT);
      while (__hip_atomic_load(xbar, __ATOMIC_RELAXED, __HIP_MEMORY_SCOPE_AGENT) < 32u * (w + 1))
        __builtin_amdgcn_s_sleep(1);
    }
    __syncthreads();

    if (s >= 0 && s < NSCAN) {
      const unsigned short* baseU = stg + (size_t)lyr * BH;
      const unsigned short* baseW = stg + (size_t)(lyr > 0 ? lyr - 1 : 0) * BH;
      const unsigned short* aU = baseU + (size_t)l15 * H + 8 * lhi;
      const unsigned short* aW = baseW + (size_t)l15 * H + 8 * lhi;

      f32x4 acc[4][4];
#pragma unroll
      for (int m = 0; m < 4; ++m)
#pragma unroll
        for (int n = 0; n < 4; ++n) acc[m][n] = (f32x4){0.f, 0.f, 0.f, 0.f};

      short8 A[2][4];

#define KCOL0(c)  (96 * q + 32 * (c))                         // LDS-weight chunks (c<3)
#define KCOLR(c)  (KL + 160 * q + 32 * ((c) - 3))             // reg-weight chunks lyr>0
#define ISSUE(buf, k) { \
    const unsigned short* _p = ((k) < 1024) ? (aU + (k)) : (aW + ((k) - 1024)); \
    ldg16_l2(&A[buf][0], _p); \
    ldg16_l2(&A[buf][1], _p + 16 * H); \
    ldg16_l2(&A[buf][2], _p + 32 * H); \
    ldg16_l2(&A[buf][3], _p + 48 * H); }

      if (lyr > 0) {
        ISSUE(0, KCOL0(0));
        ISSUE(1, KCOL0(1));
#pragma unroll
        for (int c = 0; c < 8; ++c) {
          if (c < 7) VMWAIT4; else VMWAIT0;
          if (c < 3) {
            const int kk = KCOL0(c);
#pragma unroll
            for (int n = 0; n < 4; ++n) {
              const int byteoff = (((n * 16 + l15) * KL + kk + 8 * lhi) * 2) ^ ((l15 & 7) << 4);
              short8 bb = *(const short8*)((const char*)WuL + byteoff);
#pragma unroll
              for (int m = 0; m < 4; ++m)
                acc[m][n] = __builtin_amdgcn_mfma_f32_16x16x32_bf16(A[c & 1][m], bb, acc[m][n], 0, 0, 0);
            }
          } else {
#pragma unroll
            for (int n = 0; n < 4; ++n)
#pragma unroll
              for (int m = 0; m < 4; ++m)
                acc[m][n] = __builtin_amdgcn_mfma_f32_16x16x32_bf16(A[c & 1][m], wreg[c - 3][n], acc[m][n], 0, 0, 0);
          }
          if (c + 2 < 8) {
            const int k2 = (c + 2 < 3) ? KCOL0(c + 2) : KCOLR(c + 2);
            ISSUE(c & 1, k2);
          }
        }
      } else {
        ISSUE(0, KCOL0(0));
        ISSUE(1, KCOL0(1));
#pragma unroll
        for (int c = 0; c < 4; ++c) {
          if (c < 3) VMWAIT4; else VMWAIT0;
          if (c < 3) {
            const int kk = KCOL0(c);
#pragma unroll
            for (int n = 0; n < 4; ++n) {
              const int byteoff = (((n * 16 + l15) * KL + kk + 8 * lhi) * 2) ^ ((l15 & 7) << 4);
              short8 bb = *(const short8*)((const char*)WuL + byteoff);
#pragma unroll
              for (int m = 0; m < 4; ++m)
                acc[m][n] = __builtin_amdgcn_mfma_f32_16x16x32_bf16(A[c & 1][m], bb, acc[m][n], 0, 0, 0);
            }
          } else {
#pragma unroll
            for (int n = 0; n < 4; ++n)
#pragma unroll
              for (int m = 0; m < 4; ++m)
                acc[m][n] = __builtin_amdgcn_mfma_f32_16x16x32_bf16(A[c & 1][m], wreg[0][n], acc[m][n], 0, 0, 0);
          }
          if (c + 2 < 4) ISSUE(c & 1, KCOL0(c + 2));
        }
      }
#undef ISSUE
#undef KCOL0
#undef KCOLR

      // transposed vectorized reduce: 8 partials -> red[0] + red[1]
      __syncthreads();
      {
        const int rr = q >> 1;
        float* tile = red[q & 1];
        for (int r = 0; r < 4; ++r) {
          if (rr == r) {
#pragma unroll
            for (int m = 0; m < 4; ++m)
#pragma unroll
              for (int n = 0; n < 4; ++n) {
                float* p = &tile[(n * 16 + l15) * RSTR + m * 16 + lhi * 4];
                if (r == 0) *(f32x4*)p = acc[m][n];
                else { f32x4 v = *(f32x4*)p; v += acc[m][n]; *(f32x4*)p = v; }
              }
          }
          __syncthreads();
        }
      }

      // fused LSTM cell (2 adjacent hidden units per thread)
      {
        const int u = tid * 2;
        const int b = u >> 4, jj = u & 15;  // jj even
        unsigned short hyv[2];
#pragma unroll
        for (int e = 0; e < 2; ++e) {
          const int j2 = jj + e;
          const float ig = red[0][(0 * 16 + j2) * RSTR + b] + red[1][(0 * 16 + j2) * RSTR + b];
          const float fg = red[0][(1 * 16 + j2) * RSTR + b] + red[1][(1 * 16 + j2) * RSTR + b];
          const float gg = red[0][(2 * 16 + j2) * RSTR + b] + red[1][(2 * 16 + j2) * RSTR + b];
          const float og = red[0][(3 * 16 + j2) * RSTR + b] + red[1][(3 * 16 + j2) * RSTR + b];
          const float i_ = sigmoidf_(ig);
          const float f_ = sigmoidf_(fg);
          const float g_ = tanhf_(gg);
          const float o_ = sigmoidf_(og);
          const float cv = f_ * cS[b * 16 + j2] + i_ * g_;
          cS[b * 16 + j2] = cv;
          hyv[e] = f2bf(o_ * tanhf_(cv));
        }
        const unsigned packed = (unsigned)hyv[0] | ((unsigned)hyv[1] << 16);
        st_h4(hwr + (size_t)lyr * BH + (size_t)b * H + jt * 16 + jj, packed);
        if (lyr == 3)   // history for the batched output projection (t = s+1)
          *(unsigned*)(hist + (size_t)(s + 1) * BH + (size_t)b * H + jt * 16 + jj) = packed;
      }
    }

    gridbar(bar, barn++);
  }
}

// ---------------- batched output projection: out[t] = hist[t] @ L^T ----------------
// M = 128*64 = 8192 rows, N = 512, K = 1024. grid = 128 Mtiles x 8 Ntiles, 256 thr.
__global__ __launch_bounds__(256) void proj_kernel(
    const unsigned short* __restrict__ hist, const float* __restrict__ Lm,
    float* __restrict__ out) {
  __shared__ __align__(16) unsigned short As[64 * 136];
  const int tid = threadIdx.x;
  const int q = tid >> 6;
  const int lane = tid & 63;
  const int l15 = lane & 15;
  const int lhi = lane >> 4;
  const int mt = blockIdx.x >> 3;
  const int nt = blockIdx.x & 7;

  f32x4 acc[4];
#pragma unroll
  for (int m = 0; m < 4; ++m) acc[m] = (f32x4){0.f, 0.f, 0.f, 0.f};

  for (int kb = 0; kb < 8; ++kb) {
    __syncthreads();
#pragma unroll
    for (int i = 0; i < 4; ++i) {
      int g = tid + 256 * i;
      int row = g >> 4, cu = g & 15;
      *(short8*)(&As[row * 136 + cu * 8]) =
          *(const short8*)(&hist[((size_t)mt * 64 + row) * H + kb * 128 + cu * 8]);
    }
    __syncthreads();
#pragma unroll
    for (int kk = 0; kk < 4; ++kk) {
      const int ko = kk * 32 + 8 * lhi;
      const float* src = Lm + ((size_t)nt * 64 + q * 16 + l15) * H + kb * 128 + ko;
      short8 bb = pack8(*(const float4*)src, *(const float4*)(src + 4));
#pragma unroll
      for (int m = 0; m < 4; ++m) {
        short8 a = *(const short8*)(&As[(m * 16 + l15) * 136 + ko]);
        acc[m] = __builtin_amdgcn_mfma_f32_16x16x32_bf16(a, bb, acc[m], 0, 0, 0);
      }
    }
  }
  const int col = nt * 64 + q * 16 + l15;
#pragma unroll
  for (int m = 0; m < 4; ++m)
#pragma unroll
    for (int j = 0; j < 4; ++j) {
      const int row = mt * 64 + m * 16 + lhi * 4 + j;
      out[(size_t)row * NOUTD + col] = acc[m][j];
    }
}

extern "C" void kernel_launch(void* const* d_in, const int* in_sizes, int n_in,
                              void* d_out, int out_size, void* d_ws, size_t ws_size,
                              hipStream_t stream) {
  const float* hx = (const float*)d_in[0];
  const float* cx = (const float*)d_in[1];
  const float* Wm = (const float*)d_in[2];
  const float* Um = (const float*)d_in[3];
  const float* Lm = (const float*)d_in[4];
  float* out = (float*)d_out;

  char* ws = (char*)d_ws;
  unsigned short* hb = (unsigned short*)ws;                        // 1 MB ping-pong h
  unsigned* bar = (unsigned*)(ws + (1 << 20));                     // 4 KB barrier+elect+xbar
  unsigned short* stgAll = (unsigned short*)(ws + (1 << 20) + 65536);  // 4 MB XCD stages
  unsigned short* hist = (unsigned short*)(ws + (1 << 20) + 65536 + (4 << 20));  // 16 MB

  hipMemsetAsync(bar, 0, 4096, stream);

  void* args[] = {(void*)&hx, (void*)&cx, (void*)&Wm, (void*)&Um,
                  (void*)&hb, (void*)&hist, (void*)&bar, (void*)&stgAll};
  hipLaunchCooperativeKernel((const void*)lstm_persist, dim3(256), dim3(512),
                             args, 0, stream);
  proj_kernel<<<dim3(1024), dim3(256), 0, stream>>>(hist, Lm, out);
}

// Round 10
// 1718.087 us; speedup vs baseline: 1.9083x; 1.5333x over previous
//
#include <hip/hip_runtime.h>

// Persistent cooperative LSTM decoder. NLAYERS=4, NHID=1024, NOUT=512, BSZ=64, STEPS=128.
// 256 blocks x 512 threads, 1 block/CU. Block (lyr, jt) owns 16 hidden cols of layer lyr.
// Round-10: POINT-TO-POINT DATAFLOW sync (no global barrier, no convoy).
//  - h state: 16-slot ring per layer (8MB, IC-resident, sc1 stores) - no ping-pong WAR
//  - completion flags: flag[row][l][jt] set-once uint (plain sc1 store, NO RMW)
//    row w = "wave w-1 done"; init posts row 0.
//  - wait: 192 threads spin in parallel (own layer @row w, layer below @row w,
//    WAR: layer above @row w-14 when w>=16); one IC latency per poll.
//  - deadlock-free: min-progress block's waits are all on already-posted rows.
// Compute identical to round 6: 96KB LDS weights + reg weights, depth-2 vmcnt
// A-pipeline (sc0 sc1 IC loads), transposed LDS reduce, LDS cell state, proj_kernel.

#define H      1024
#define B      64
#define NL     4
#define BH     (B * H)
#define NOUTD  512
#define NSCAN  127
#define NWAVES 130
#define RSTR   76   // transposed reduce stride (floats)
#define KL     768  // K columns resident in LDS per gate-row

typedef __attribute__((ext_vector_type(8))) short short8;
typedef __attribute__((ext_vector_type(4))) float f32x4;

__device__ __forceinline__ unsigned short f2bf(float x) {
  union { float f; unsigned int u; } v; v.f = x;
  unsigned int r = v.u + 0x7FFFu + ((v.u >> 16) & 1u);
  return (unsigned short)(r >> 16);
}
__device__ __forceinline__ short8 pack8(float4 a, float4 b) {
  short8 r;
  r[0] = (short)f2bf(a.x); r[1] = (short)f2bf(a.y);
  r[2] = (short)f2bf(a.z); r[3] = (short)f2bf(a.w);
  r[4] = (short)f2bf(b.x); r[5] = (short)f2bf(b.y);
  r[6] = (short)f2bf(b.z); r[7] = (short)f2bf(b.w);
  return r;
}
__device__ __forceinline__ float sigmoidf_(float x) {
  return 1.0f / (1.0f + __expf(-x));
}
__device__ __forceinline__ float tanhf_(float x) {
  float ax = fabsf(x);
  float t = __expf(-2.0f * ax);
  float r = 1.0f - 2.0f * t / (1.0f + t);
  return copysignf(r, x);
}

// IC-coherent 16B load (L1+L2 bypass). Consume only after a vmcnt wait.
__device__ __forceinline__ void ldg16(short8* d, const unsigned short* p) {
  asm volatile("global_load_dwordx4 %0, %1, off sc0 sc1" : "=v"(*d) : "v"(p));
}
#define VMWAIT4 do { asm volatile("s_waitcnt vmcnt(4)" ::: "memory"); \
                     __builtin_amdgcn_sched_barrier(0); } while (0)
#define VMWAIT0 do { asm volatile("s_waitcnt vmcnt(0)" ::: "memory"); \
                     __builtin_amdgcn_sched_barrier(0); } while (0)

__device__ __forceinline__ void st_h4(unsigned short* p, unsigned v) {
  __hip_atomic_store((unsigned*)p, v, __ATOMIC_RELAXED, __HIP_MEMORY_SCOPE_AGENT);
}

__global__ __launch_bounds__(512, 2)
__attribute__((amdgpu_waves_per_eu(2, 2)))
void lstm_persist(
    const float* __restrict__ hx, const float* __restrict__ cx,
    const float* __restrict__ Wm, const float* __restrict__ Um,
    unsigned short* __restrict__ hr, unsigned short* __restrict__ hist,
    unsigned* __restrict__ flags) {
  __shared__ __align__(16) unsigned short WuL[64 * KL];    // 96 KB swizzled gate weights
  __shared__ __align__(16) float red[2][64 * RSTR];        // 38.9 KB transposed reduce
  __shared__ float cS[B * 16];                             // 4 KB cell state

  const int tid = threadIdx.x;
  const int q = tid >> 6;            // wave 0..7
  const int lane = tid & 63;
  const int l15 = lane & 15;
  const int lhi = lane >> 4;
  const int bid = blockIdx.x;
  const int lyr = bid >> 6;          // 0..3
  const int jt = bid & 63;           // 16-col group

  // ring slot pointer: layer l, slot s (16 slots x 128KB per layer)
#define SLOT(l, s) (hr + ((size_t)((l) * 16 + (s))) * BH)
  // flag row w: 4 layers x 64 blocks, 1KB per row
#define FROW(w) (flags + (size_t)(w) * 256)

  // ---------------- init: h -> ring slot (lyr-1)&15 + c + hist[0] ----------------
  {
    const int u = tid * 2;
    const int b = u >> 4, jj = u & 15;      // jj even
    const size_t gi = (size_t)lyr * BH + (size_t)b * H + jt * 16 + jj;
    const unsigned hv = (unsigned)f2bf(hx[gi]) | ((unsigned)f2bf(hx[gi + 1]) << 16);
    st_h4(SLOT(lyr, (lyr - 1) & 15) + (size_t)b * H + jt * 16 + jj, hv);
    if (lyr == 3) *(unsigned*)(hist + (size_t)b * H + jt * 16 + jj) = hv;
    cS[b * 16 + jj] = cx[gi];
    cS[b * 16 + jj + 1] = cx[gi + 1];
  }

  // ---------------- weights: LDS part (K 0..767), swizzled ----------------
  {
    const int lr = tid >> 3;                 // local gate row 0..63
    const int kb0 = (tid & 7) * 96;          // K base (96 cols per thread)
    const int gr = (lr >> 4) * 1024 + jt * 16 + (lr & 15);
    const float* src = Um + ((size_t)lyr * 4096 + gr) * 1024 + kb0;
#pragma unroll
    for (int jc = 0; jc < 12; ++jc) {
      float4 f0 = *(const float4*)(src + jc * 8);
      float4 f1 = *(const float4*)(src + jc * 8 + 4);
      int byteoff = ((lr * KL + kb0 + jc * 8) * 2) ^ ((lr & 7) << 4);
      *(short8*)((char*)WuL + byteoff) = pack8(f0, f1);
    }
  }

  // ---------------- register weights (K >= 768): 5 chunks lyr>0, 1 chunk lyr0 ----------------
  short8 wreg[5][4];
  if (lyr == 0) {
    const int kk = KL + 32 * q + 8 * lhi;    // 768..1023
#pragma unroll
    for (int n = 0; n < 4; ++n) {
      const int gr = n * 1024 + jt * 16 + l15;
      const float* src = Um + (size_t)gr * 1024 + kk;
      wreg[0][n] = pack8(*(const float4*)src, *(const float4*)(src + 4));
    }
  } else {
#pragma unroll
    for (int c = 0; c < 5; ++c) {
      const int kk = KL + 160 * q + 32 * c + 8 * lhi;   // 768..2047
#pragma unroll
      for (int n = 0; n < 4; ++n) {
        const int gr = n * 1024 + jt * 16 + l15;
        const float* src = (kk < 1024)
            ? (Um + ((size_t)lyr * 4096 + gr) * 1024 + kk)
            : (Wm + ((size_t)(lyr - 1) * 4096 + gr) * 1024 + (kk - 1024));
        wreg[c][n] = pack8(*(const float4*)src, *(const float4*)(src + 4));
      }
    }
  }

  // ---------------- post init flag (row 0) ----------------
  asm volatile("s_waitcnt vmcnt(0)" ::: "memory");
  __syncthreads();
  if (tid == 0)
    __hip_atomic_store(FROW(0) + lyr * 64 + jt, 1u,
                       __ATOMIC_RELAXED, __HIP_MEMORY_SCOPE_AGENT);

  // ---------------- wavefront loop ----------------
  for (int w = 0; w < NWAVES; ++w) {
    const int s = w - lyr;

    if (s >= 0 && s < NSCAN) {
      // ---- dataflow wait: 192 threads spin in parallel, one flag each ----
      {
        const unsigned* row = FROW(w);
        const unsigned* myf = nullptr;
        if (tid < 64) {
          myf = row + lyr * 64 + tid;                       // own layer @ w (RAW, U-part)
        } else if (tid < 128) {
          if (lyr > 0) myf = row + (lyr - 1) * 64 + (tid - 64);  // layer below @ w (RAW, W-part)
        } else if (tid < 192) {
          if (lyr < 3 && w >= 16)                            // WAR: ring reuse of slot w&15
            myf = FROW(w - 14) + (lyr + 1) * 64 + (tid - 128);
        }
        if (myf)
          while (!__hip_atomic_load(myf, __ATOMIC_RELAXED, __HIP_MEMORY_SCOPE_AGENT))
            __builtin_amdgcn_s_sleep(1);
      }
      __syncthreads();

      const unsigned short* baseU = SLOT(lyr, (w - 1) & 15);
      const unsigned short* baseW = SLOT(lyr > 0 ? lyr - 1 : 0, (w - 1) & 15);
      const unsigned short* aU = baseU + (size_t)l15 * H + 8 * lhi;
      const unsigned short* aW = baseW + (size_t)l15 * H + 8 * lhi;

      f32x4 acc[4][4];
#pragma unroll
      for (int m = 0; m < 4; ++m)
#pragma unroll
        for (int n = 0; n < 4; ++n) acc[m][n] = (f32x4){0.f, 0.f, 0.f, 0.f};

      short8 A[2][4];

#define KCOL0(c)  (96 * q + 32 * (c))                         // LDS-weight chunks (c<3)
#define KCOLR(c)  (KL + 160 * q + 32 * ((c) - 3))             // reg-weight chunks lyr>0
#define ISSUE(buf, k) { \
    const unsigned short* _p = ((k) < 1024) ? (aU + (k)) : (aW + ((k) - 1024)); \
    ldg16(&A[buf][0], _p); \
    ldg16(&A[buf][1], _p + 16 * H); \
    ldg16(&A[buf][2], _p + 32 * H); \
    ldg16(&A[buf][3], _p + 48 * H); }

      if (lyr > 0) {
        ISSUE(0, KCOL0(0));
        ISSUE(1, KCOL0(1));
#pragma unroll
        for (int c = 0; c < 8; ++c) {
          if (c < 7) VMWAIT4; else VMWAIT0;
          if (c < 3) {
            const int kk = KCOL0(c);
#pragma unroll
            for (int n = 0; n < 4; ++n) {
              const int byteoff = (((n * 16 + l15) * KL + kk + 8 * lhi) * 2) ^ ((l15 & 7) << 4);
              short8 bb = *(const short8*)((const char*)WuL + byteoff);
#pragma unroll
              for (int m = 0; m < 4; ++m)
                acc[m][n] = __builtin_amdgcn_mfma_f32_16x16x32_bf16(A[c & 1][m], bb, acc[m][n], 0, 0, 0);
            }
          } else {
#pragma unroll
            for (int n = 0; n < 4; ++n)
#pragma unroll
              for (int m = 0; m < 4; ++m)
                acc[m][n] = __builtin_amdgcn_mfma_f32_16x16x32_bf16(A[c & 1][m], wreg[c - 3][n], acc[m][n], 0, 0, 0);
          }
          if (c + 2 < 8) {
            const int k2 = (c + 2 < 3) ? KCOL0(c + 2) : KCOLR(c + 2);
            ISSUE(c & 1, k2);
          }
        }
      } else {
        ISSUE(0, KCOL0(0));
        ISSUE(1, KCOL0(1));
#pragma unroll
        for (int c = 0; c < 4; ++c) {
          if (c < 3) VMWAIT4; else VMWAIT0;
          if (c < 3) {
            const int kk = KCOL0(c);
#pragma unroll
            for (int n = 0; n < 4; ++n) {
              const int byteoff = (((n * 16 + l15) * KL + kk + 8 * lhi) * 2) ^ ((l15 & 7) << 4);
              short8 bb = *(const short8*)((const char*)WuL + byteoff);
#pragma unroll
              for (int m = 0; m < 4; ++m)
                acc[m][n] = __builtin_amdgcn_mfma_f32_16x16x32_bf16(A[c & 1][m], bb, acc[m][n], 0, 0, 0);
            }
          } else {
#pragma unroll
            for (int n = 0; n < 4; ++n)
#pragma unroll
              for (int m = 0; m < 4; ++m)
                acc[m][n] = __builtin_amdgcn_mfma_f32_16x16x32_bf16(A[c & 1][m], wreg[0][n], acc[m][n], 0, 0, 0);
          }
          if (c + 2 < 4) ISSUE(c & 1, KCOL0(c + 2));
        }
      }
#undef ISSUE
#undef KCOL0
#undef KCOLR

      // transposed vectorized reduce: 8 partials -> red[0] + red[1]
      __syncthreads();
      {
        const int rr = q >> 1;
        float* tile = red[q & 1];
        for (int r = 0; r < 4; ++r) {
          if (rr == r) {
#pragma unroll
            for (int m = 0; m < 4; ++m)
#pragma unroll
              for (int n = 0; n < 4; ++n) {
                float* p = &tile[(n * 16 + l15) * RSTR + m * 16 + lhi * 4];
                if (r == 0) *(f32x4*)p = acc[m][n];
                else { f32x4 v = *(f32x4*)p; v += acc[m][n]; *(f32x4*)p = v; }
              }
          }
          __syncthreads();
        }
      }

      // fused LSTM cell (2 adjacent hidden units per thread)
      {
        const int u = tid * 2;
        const int b = u >> 4, jj = u & 15;  // jj even
        unsigned short hyv[2];
#pragma unroll
        for (int e = 0; e < 2; ++e) {
          const int j2 = jj + e;
          const float ig = red[0][(0 * 16 + j2) * RSTR + b] + red[1][(0 * 16 + j2) * RSTR + b];
          const float fg = red[0][(1 * 16 + j2) * RSTR + b] + red[1][(1 * 16 + j2) * RSTR + b];
          const float gg = red[0][(2 * 16 + j2) * RSTR + b] + red[1][(2 * 16 + j2) * RSTR + b];
          const float og = red[0][(3 * 16 + j2) * RSTR + b] + red[1][(3 * 16 + j2) * RSTR + b];
          const float i_ = sigmoidf_(ig);
          const float f_ = sigmoidf_(fg);
          const float g_ = tanhf_(gg);
          const float o_ = sigmoidf_(og);
          const float cv = f_ * cS[b * 16 + j2] + i_ * g_;
          cS[b * 16 + j2] = cv;
          hyv[e] = f2bf(o_ * tanhf_(cv));
        }
        const unsigned packed = (unsigned)hyv[0] | ((unsigned)hyv[1] << 16);
        st_h4(SLOT(lyr, w & 15) + (size_t)b * H + jt * 16 + jj, packed);
        if (lyr == 3)   // history for the batched output projection (t = s+1)
          *(unsigned*)(hist + (size_t)(s + 1) * BH + (size_t)b * H + jt * 16 + jj) = packed;
      }
    }

    // ---- drain + post flag row w+1 (every wave, active or idle) ----
    asm volatile("s_waitcnt vmcnt(0)" ::: "memory");
    __syncthreads();
    if (tid == 0)
      __hip_atomic_store(FROW(w + 1) + lyr * 64 + jt, 1u,
                         __ATOMIC_RELAXED, __HIP_MEMORY_SCOPE_AGENT);
  }
#undef SLOT
#undef FROW
}

// ---------------- batched output projection: out[t] = hist[t] @ L^T ----------------
// M = 128*64 = 8192 rows, N = 512, K = 1024. grid = 128 Mtiles x 8 Ntiles, 256 thr.
__global__ __launch_bounds__(256) void proj_kernel(
    const unsigned short* __restrict__ hist, const float* __restrict__ Lm,
    float* __restrict__ out) {
  __shared__ __align__(16) unsigned short As[64 * 136];
  const int tid = threadIdx.x;
  const int q = tid >> 6;
  const int lane = tid & 63;
  const int l15 = lane & 15;
  const int lhi = lane >> 4;
  const int mt = blockIdx.x >> 3;
  const int nt = blockIdx.x & 7;

  f32x4 acc[4];
#pragma unroll
  for (int m = 0; m < 4; ++m) acc[m] = (f32x4){0.f, 0.f, 0.f, 0.f};

  for (int kb = 0; kb < 8; ++kb) {
    __syncthreads();
#pragma unroll
    for (int i = 0; i < 4; ++i) {
      int g = tid + 256 * i;
      int row = g >> 4, cu = g & 15;
      *(short8*)(&As[row * 136 + cu * 8]) =
          *(const short8*)(&hist[((size_t)mt * 64 + row) * H + kb * 128 + cu * 8]);
    }
    __syncthreads();
#pragma unroll
    for (int kk = 0; kk < 4; ++kk) {
      const int ko = kk * 32 + 8 * lhi;
      const float* src = Lm + ((size_t)nt * 64 + q * 16 + l15) * H + kb * 128 + ko;
      short8 bb = pack8(*(const float4*)src, *(const float4*)(src + 4));
#pragma unroll
      for (int m = 0; m < 4; ++m) {
        short8 a = *(const short8*)(&As[(m * 16 + l15) * 136 + ko]);
        acc[m] = __builtin_amdgcn_mfma_f32_16x16x32_bf16(a, bb, acc[m], 0, 0, 0);
      }
    }
  }
  const int col = nt * 64 + q * 16 + l15;
#pragma unroll
  for (int m = 0; m < 4; ++m)
#pragma unroll
    for (int j = 0; j < 4; ++j) {
      const int row = mt * 64 + m * 16 + lhi * 4 + j;
      out[(size_t)row * NOUTD + col] = acc[m][j];
    }
}

extern "C" void kernel_launch(void* const* d_in, const int* in_sizes, int n_in,
                              void* d_out, int out_size, void* d_ws, size_t ws_size,
                              hipStream_t stream) {
  const float* hx = (const float*)d_in[0];
  const float* cx = (const float*)d_in[1];
  const float* Wm = (const float*)d_in[2];
  const float* Um = (const float*)d_in[3];
  const float* Lm = (const float*)d_in[4];
  float* out = (float*)d_out;

  char* ws = (char*)d_ws;
  unsigned short* hr = (unsigned short*)ws;                     // 8 MB: 4 layers x 16-slot ring
  unsigned* flags = (unsigned*)(ws + (8 << 20));                // 256 KB flag rows
  unsigned short* hist = (unsigned short*)(ws + (9 << 20));     // 16 MB hy3 history

  hipMemsetAsync(flags, 0, 262144, stream);

  void* args[] = {(void*)&hx, (void*)&cx, (void*)&Wm, (void*)&Um,
                  (void*)&hr, (void*)&hist, (void*)&flags};
  hipLaunchCooperativeKernel((const void*)lstm_persist, dim3(256), dim3(512),
                             args, 0, stream);
  proj_kernel<<<dim3(1024), dim3(256), 0, stream>>>(hist, Lm, out);
}

// Round 11
// 1668.914 us; speedup vs baseline: 1.9646x; 1.0295x over previous
//
#include <hip/hip_runtime.h>

// Persistent cooperative LSTM decoder. NLAYERS=4, NHID=1024, NOUT=512, BSZ=64, STEPS=128.
// 256 blocks x 512 threads, 1 block/CU. Block (lyr, jt) owns 16 hidden cols of layer lyr.
// Round-11: MONOTONIC (write-once) h slabs -> PLAIN L2-CACHED A-loads.
//  - h[l] after wave w lives at slab position p=w+1 (init at p=l). 4 layers x 128
//    positions x 128KB = 64 MiB, each address written EXACTLY ONCE (sc1 -> IC).
//  - consumers read with plain cached loads: virgin addresses + flag-gated reads
//    => no L1/L2 copy can predate the write => caching is always correct, zero
//    coherence ops. Each h line now fetched from IC ~8x (once per XCD) instead of
//    ~64x (once per block); other blocks hit local L2 (~200cy vs ~900cy).
//  - WAR hazard gone (nothing overwritten): dataflow wait is RAW-only.
//  - layer-3 slab IS the projection history (hist buffer deleted).
// Sync: r10 p2p set-once flags (== barrier perf, kept for skew absorption).
// Compute identical to r6/r10: 96KB LDS weights + reg weights, depth-2 vmcnt
// A-pipeline, transposed LDS reduce, LDS cell state, separate proj_kernel.

#define H      1024
#define B      64
#define NL     4
#define BH     (B * H)
#define NOUTD  512
#define NSCAN  127
#define NWAVES 130
#define RSTR   76   // transposed reduce stride (floats)
#define KL     768  // K columns resident in LDS per gate-row

typedef __attribute__((ext_vector_type(8))) short short8;
typedef __attribute__((ext_vector_type(4))) float f32x4;

__device__ __forceinline__ unsigned short f2bf(float x) {
  union { float f; unsigned int u; } v; v.f = x;
  unsigned int r = v.u + 0x7FFFu + ((v.u >> 16) & 1u);
  return (unsigned short)(r >> 16);
}
__device__ __forceinline__ short8 pack8(float4 a, float4 b) {
  short8 r;
  r[0] = (short)f2bf(a.x); r[1] = (short)f2bf(a.y);
  r[2] = (short)f2bf(a.z); r[3] = (short)f2bf(a.w);
  r[4] = (short)f2bf(b.x); r[5] = (short)f2bf(b.y);
  r[6] = (short)f2bf(b.z); r[7] = (short)f2bf(b.w);
  return r;
}
__device__ __forceinline__ float sigmoidf_(float x) {
  return 1.0f / (1.0f + __expf(-x));
}
__device__ __forceinline__ float tanhf_(float x) {
  float ax = fabsf(x);
  float t = __expf(-2.0f * ax);
  float r = 1.0f - 2.0f * t / (1.0f + t);
  return copysignf(r, x);
}

// PLAIN cached 16B load (L1+L2). Safe because h slabs are write-once (see header).
__device__ __forceinline__ void ldg16(short8* d, const unsigned short* p) {
  asm volatile("global_load_dwordx4 %0, %1, off" : "=v"(*d) : "v"(p));
}
#define VMWAIT4 do { asm volatile("s_waitcnt vmcnt(4)" ::: "memory"); \
                     __builtin_amdgcn_sched_barrier(0); } while (0)
#define VMWAIT0 do { asm volatile("s_waitcnt vmcnt(0)" ::: "memory"); \
                     __builtin_amdgcn_sched_barrier(0); } while (0)

__device__ __forceinline__ void st_h4(unsigned short* p, unsigned v) {
  __hip_atomic_store((unsigned*)p, v, __ATOMIC_RELAXED, __HIP_MEMORY_SCOPE_AGENT);
}

__global__ __launch_bounds__(512, 2)
__attribute__((amdgpu_waves_per_eu(2, 2)))
void lstm_persist(
    const float* __restrict__ hx, const float* __restrict__ cx,
    const float* __restrict__ Wm, const float* __restrict__ Um,
    unsigned short* __restrict__ hmon, unsigned* __restrict__ flags) {
  __shared__ __align__(16) unsigned short WuL[64 * KL];    // 96 KB swizzled gate weights
  __shared__ __align__(16) float red[2][64 * RSTR];        // 38.9 KB transposed reduce
  __shared__ float cS[B * 16];                             // 4 KB cell state

  const int tid = threadIdx.x;
  const int q = tid >> 6;            // wave 0..7
  const int lane = tid & 63;
  const int l15 = lane & 15;
  const int lhi = lane >> 4;
  const int bid = blockIdx.x;
  const int lyr = bid >> 6;          // 0..3
  const int jt = bid & 63;           // 16-col group

  // monotonic slab: layer l holds positions l..l+127; addr index = l*128 + (p-l)
#define HSL(l, p) (hmon + ((size_t)(l) * 128 + (size_t)((p) - (l))) * BH)
  // flag row w: 4 layers x 64 blocks, 1KB per row
#define FROW(w) (flags + (size_t)(w) * 256)

  // ---------------- init: h -> slab position lyr + c ----------------
  {
    const int u = tid * 2;
    const int b = u >> 4, jj = u & 15;      // jj even
    const size_t gi = (size_t)lyr * BH + (size_t)b * H + jt * 16 + jj;
    const unsigned hv = (unsigned)f2bf(hx[gi]) | ((unsigned)f2bf(hx[gi + 1]) << 16);
    st_h4(HSL(lyr, lyr) + (size_t)b * H + jt * 16 + jj, hv);
    cS[b * 16 + jj] = cx[gi];
    cS[b * 16 + jj + 1] = cx[gi + 1];
  }

  // ---------------- weights: LDS part (K 0..767), swizzled ----------------
  {
    const int lr = tid >> 3;                 // local gate row 0..63
    const int kb0 = (tid & 7) * 96;          // K base (96 cols per thread)
    const int gr = (lr >> 4) * 1024 + jt * 16 + (lr & 15);
    const float* src = Um + ((size_t)lyr * 4096 + gr) * 1024 + kb0;
#pragma unroll
    for (int jc = 0; jc < 12; ++jc) {
      float4 f0 = *(const float4*)(src + jc * 8);
      float4 f1 = *(const float4*)(src + jc * 8 + 4);
      int byteoff = ((lr * KL + kb0 + jc * 8) * 2) ^ ((lr & 7) << 4);
      *(short8*)((char*)WuL + byteoff) = pack8(f0, f1);
    }
  }

  // ---------------- register weights (K >= 768): 5 chunks lyr>0, 1 chunk lyr0 ----------------
  short8 wreg[5][4];
  if (lyr == 0) {
    const int kk = KL + 32 * q + 8 * lhi;    // 768..1023
#pragma unroll
    for (int n = 0; n < 4; ++n) {
      const int gr = n * 1024 + jt * 16 + l15;
      const float* src = Um + (size_t)gr * 1024 + kk;
      wreg[0][n] = pack8(*(const float4*)src, *(const float4*)(src + 4));
    }
  } else {
#pragma unroll
    for (int c = 0; c < 5; ++c) {
      const int kk = KL + 160 * q + 32 * c + 8 * lhi;   // 768..2047
#pragma unroll
      for (int n = 0; n < 4; ++n) {
        const int gr = n * 1024 + jt * 16 + l15;
        const float* src = (kk < 1024)
            ? (Um + ((size_t)lyr * 4096 + gr) * 1024 + kk)
            : (Wm + ((size_t)(lyr - 1) * 4096 + gr) * 1024 + (kk - 1024));
        wreg[c][n] = pack8(*(const float4*)src, *(const float4*)(src + 4));
      }
    }
  }

  // ---------------- post init flag (row 0) ----------------
  asm volatile("s_waitcnt vmcnt(0)" ::: "memory");
  __syncthreads();
  if (tid == 0)
    __hip_atomic_store(FROW(0) + lyr * 64 + jt, 1u,
                       __ATOMIC_RELAXED, __HIP_MEMORY_SCOPE_AGENT);

  // ---------------- wavefront loop ----------------
  for (int w = 0; w < NWAVES; ++w) {
    const int s = w - lyr;

    if (s >= 0 && s < NSCAN) {
      // ---- dataflow wait (RAW only): 128 threads spin in parallel ----
      {
        const unsigned* row = FROW(w);
        const unsigned* myf = nullptr;
        if (tid < 64) {
          myf = row + lyr * 64 + tid;                            // own layer @ w
        } else if (tid < 128) {
          if (lyr > 0) myf = row + (lyr - 1) * 64 + (tid - 64);  // layer below @ w
        }
        if (myf)
          while (!__hip_atomic_load(myf, __ATOMIC_RELAXED, __HIP_MEMORY_SCOPE_AGENT))
            __builtin_amdgcn_s_sleep(1);
      }
      __syncthreads();

      const unsigned short* baseU = HSL(lyr, w);
      const unsigned short* baseW = (lyr > 0) ? HSL(lyr - 1, w) : HSL(lyr, w);
      const unsigned short* aU = baseU + (size_t)l15 * H + 8 * lhi;
      const unsigned short* aW = baseW + (size_t)l15 * H + 8 * lhi;

      f32x4 acc[4][4];
#pragma unroll
      for (int m = 0; m < 4; ++m)
#pragma unroll
        for (int n = 0; n < 4; ++n) acc[m][n] = (f32x4){0.f, 0.f, 0.f, 0.f};

      short8 A[2][4];

#define KCOL0(c)  (96 * q + 32 * (c))                         // LDS-weight chunks (c<3)
#define KCOLR(c)  (KL + 160 * q + 32 * ((c) - 3))             // reg-weight chunks lyr>0
#define ISSUE(buf, k) { \
    const unsigned short* _p = ((k) < 1024) ? (aU + (k)) : (aW + ((k) - 1024)); \
    ldg16(&A[buf][0], _p); \
    ldg16(&A[buf][1], _p + 16 * H); \
    ldg16(&A[buf][2], _p + 32 * H); \
    ldg16(&A[buf][3], _p + 48 * H); }

      if (lyr > 0) {
        ISSUE(0, KCOL0(0));
        ISSUE(1, KCOL0(1));
#pragma unroll
        for (int c = 0; c < 8; ++c) {
          if (c < 7) VMWAIT4; else VMWAIT0;
          if (c < 3) {
            const int kk = KCOL0(c);
#pragma unroll
            for (int n = 0; n < 4; ++n) {
              const int byteoff = (((n * 16 + l15) * KL + kk + 8 * lhi) * 2) ^ ((l15 & 7) << 4);
              short8 bb = *(const short8*)((const char*)WuL + byteoff);
#pragma unroll
              for (int m = 0; m < 4; ++m)
                acc[m][n] = __builtin_amdgcn_mfma_f32_16x16x32_bf16(A[c & 1][m], bb, acc[m][n], 0, 0, 0);
            }
          } else {
#pragma unroll
            for (int n = 0; n < 4; ++n)
#pragma unroll
              for (int m = 0; m < 4; ++m)
                acc[m][n] = __builtin_amdgcn_mfma_f32_16x16x32_bf16(A[c & 1][m], wreg[c - 3][n], acc[m][n], 0, 0, 0);
          }
          if (c + 2 < 8) {
            const int k2 = (c + 2 < 3) ? KCOL0(c + 2) : KCOLR(c + 2);
            ISSUE(c & 1, k2);
          }
        }
      } else {
        ISSUE(0, KCOL0(0));
        ISSUE(1, KCOL0(1));
#pragma unroll
        for (int c = 0; c < 4; ++c) {
          if (c < 3) VMWAIT4; else VMWAIT0;
          if (c < 3) {
            const int kk = KCOL0(c);
#pragma unroll
            for (int n = 0; n < 4; ++n) {
              const int byteoff = (((n * 16 + l15) * KL + kk + 8 * lhi) * 2) ^ ((l15 & 7) << 4);
              short8 bb = *(const short8*)((const char*)WuL + byteoff);
#pragma unroll
              for (int m = 0; m < 4; ++m)
                acc[m][n] = __builtin_amdgcn_mfma_f32_16x16x32_bf16(A[c & 1][m], bb, acc[m][n], 0, 0, 0);
            }
          } else {
#pragma unroll
            for (int n = 0; n < 4; ++n)
#pragma unroll
              for (int m = 0; m < 4; ++m)
                acc[m][n] = __builtin_amdgcn_mfma_f32_16x16x32_bf16(A[c & 1][m], wreg[0][n], acc[m][n], 0, 0, 0);
          }
          if (c + 2 < 4) ISSUE(c & 1, KCOL0(c + 2));
        }
      }
#undef ISSUE
#undef KCOL0
#undef KCOLR

      // transposed vectorized reduce: 8 partials -> red[0] + red[1]
      __syncthreads();
      {
        const int rr = q >> 1;
        float* tile = red[q & 1];
        for (int r = 0; r < 4; ++r) {
          if (rr == r) {
#pragma unroll
            for (int m = 0; m < 4; ++m)
#pragma unroll
              for (int n = 0; n < 4; ++n) {
                float* p = &tile[(n * 16 + l15) * RSTR + m * 16 + lhi * 4];
                if (r == 0) *(f32x4*)p = acc[m][n];
                else { f32x4 v = *(f32x4*)p; v += acc[m][n]; *(f32x4*)p = v; }
              }
          }
          __syncthreads();
        }
      }

      // fused LSTM cell (2 adjacent hidden units per thread)
      {
        const int u = tid * 2;
        const int b = u >> 4, jj = u & 15;  // jj even
        unsigned short hyv[2];
#pragma unroll
        for (int e = 0; e < 2; ++e) {
          const int j2 = jj + e;
          const float ig = red[0][(0 * 16 + j2) * RSTR + b] + red[1][(0 * 16 + j2) * RSTR + b];
          const float fg = red[0][(1 * 16 + j2) * RSTR + b] + red[1][(1 * 16 + j2) * RSTR + b];
          const float gg = red[0][(2 * 16 + j2) * RSTR + b] + red[1][(2 * 16 + j2) * RSTR + b];
          const float og = red[0][(3 * 16 + j2) * RSTR + b] + red[1][(3 * 16 + j2) * RSTR + b];
          const float i_ = sigmoidf_(ig);
          const float f_ = sigmoidf_(fg);
          const float g_ = tanhf_(gg);
          const float o_ = sigmoidf_(og);
          const float cv = f_ * cS[b * 16 + j2] + i_ * g_;
          cS[b * 16 + j2] = cv;
          hyv[e] = f2bf(o_ * tanhf_(cv));
        }
        const unsigned packed = (unsigned)hyv[0] | ((unsigned)hyv[1] << 16);
        st_h4(HSL(lyr, w + 1) + (size_t)b * H + jt * 16 + jj, packed);
      }
    }

    // ---- drain + post flag row w+1 (every wave, active or idle) ----
    asm volatile("s_waitcnt vmcnt(0)" ::: "memory");
    __syncthreads();
    if (tid == 0)
      __hip_atomic_store(FROW(w + 1) + lyr * 64 + jt, 1u,
                         __ATOMIC_RELAXED, __HIP_MEMORY_SCOPE_AGENT);
  }
#undef HSL
#undef FROW
}

// ---------------- batched output projection: out[t] = h3[t] @ L^T ----------------
// h3 history = layer-3 monotonic slab (position t+3 = slab index t). M = 8192, N = 512, K = 1024.
__global__ __launch_bounds__(256) void proj_kernel(
    const unsigned short* __restrict__ hist, const float* __restrict__ Lm,
    float* __restrict__ out) {
  __shared__ __align__(16) unsigned short As[64 * 136];
  const int tid = threadIdx.x;
  const int q = tid >> 6;
  const int lane = tid & 63;
  const int l15 = lane & 15;
  const int lhi = lane >> 4;
  const int mt = blockIdx.x >> 3;
  const int nt = blockIdx.x & 7;

  f32x4 acc[4];
#pragma unroll
  for (int m = 0; m < 4; ++m) acc[m] = (f32x4){0.f, 0.f, 0.f, 0.f};

  for (int kb = 0; kb < 8; ++kb) {
    __syncthreads();
#pragma unroll
    for (int i = 0; i < 4; ++i) {
      int g = tid + 256 * i;
      int row = g >> 4, cu = g & 15;
      *(short8*)(&As[row * 136 + cu * 8]) =
          *(const short8*)(&hist[((size_t)mt * 64 + row) * H + kb * 128 + cu * 8]);
    }
    __syncthreads();
#pragma unroll
    for (int kk = 0; kk < 4; ++kk) {
      const int ko = kk * 32 + 8 * lhi;
      const float* src = Lm + ((size_t)nt * 64 + q * 16 + l15) * H + kb * 128 + ko;
      short8 bb = pack8(*(const float4*)src, *(const float4*)(src + 4));
#pragma unroll
      for (int m = 0; m < 4; ++m) {
        short8 a = *(const short8*)(&As[(m * 16 + l15) * 136 + ko]);
        acc[m] = __builtin_amdgcn_mfma_f32_16x16x32_bf16(a, bb, acc[m], 0, 0, 0);
      }
    }
  }
  const int col = nt * 64 + q * 16 + l15;
#pragma unroll
  for (int m = 0; m < 4; ++m)
#pragma unroll
    for (int j = 0; j < 4; ++j) {
      const int row = mt * 64 + m * 16 + lhi * 4 + j;
      out[(size_t)row * NOUTD + col] = acc[m][j];
    }
}

extern "C" void kernel_launch(void* const* d_in, const int* in_sizes, int n_in,
                              void* d_out, int out_size, void* d_ws, size_t ws_size,
                              hipStream_t stream) {
  const float* hx = (const float*)d_in[0];
  const float* cx = (const float*)d_in[1];
  const float* Wm = (const float*)d_in[2];
  const float* Um = (const float*)d_in[3];
  const float* Lm = (const float*)d_in[4];
  float* out = (float*)d_out;

  char* ws = (char*)d_ws;
  unsigned* flags = (unsigned*)ws;                              // 256 KB flag rows
  unsigned short* hmon = (unsigned short*)(ws + (1 << 18));     // 64 MiB monotonic h slabs

  hipMemsetAsync(flags, 0, 262144, stream);

  void* args[] = {(void*)&hx, (void*)&cx, (void*)&Wm, (void*)&Um,
                  (void*)&hmon, (void*)&flags};
  hipLaunchCooperativeKernel((const void*)lstm_persist, dim3(256), dim3(512),
                             args, 0, stream);
  // layer-3 slab base: position t+3 lives at slab index t  => history rows = t*BH
  const unsigned short* hist = hmon + (size_t)3 * 128 * BH;
  proj_kernel<<<dim3(1024), dim3(256), 0, stream>>>(hist, Lm, out);
}